// Round 1
// 407.112 us; speedup vs baseline: 1.0314x; 1.0314x over previous
//
#include <hip/hip_runtime.h>

#define HW    16384   // 128*128
#define NCH   256     // C
#define NB    16      // batch
#define INTER 128
#define HW4   4096    // HW/4 (float4 units)

// Output: [16, 4, 128, 128] f32.
//   out[b,0]    = gelu_exact(sum_c x[b,c,:,:] * W3[c])
//   out[b,1..3] = x[b, top3_ch_r, :, :]
// psum[b] (16 KB) borrows d_out's channel-1 slot between kernels A and B
// (kernel D's gather overwrites it afterwards).

// ---------------------------------------------------------------------------
// Kernel A: fused pool + x3 pass over x (268 MB), software-pipelined.
// grid (16 tiles, 16 b), 512 threads = 8 waves/CU (2/SIMD): threads split in
// two channel groups (0-127 / 128-255) over the same 256-float4 spatial tile,
// so one wave issues loads while the other drains its shfl reduction chain.
// Per-pixel x3 partials combined via LDS; per-channel pool partials in wsum.
// ---------------------------------------------------------------------------
__global__ __launch_bounds__(512, 2) void k_pool_x3(
    const float* __restrict__ x, const float* __restrict__ W3, float* out)
{
    const int tile = blockIdx.x;
    const int b    = blockIdx.y;
    const int tid  = threadIdx.x;
    const int wave = tid >> 6, lane = tid & 63;
    const int g    = tid >> 8;        // channel group: 0 -> ch 0..127, 1 -> 128..255
    const int p    = tid & 255;       // float4-pixel within tile
    const int gofs = g << 7;          // 128*g

    __shared__ float  w3f[NCH];
    __shared__ float  wsum[8][128];   // [wave][local channel]
    __shared__ float4 comb[256];      // per-pixel x3 partial from group 1

    if (tid < NCH) w3f[tid] = W3[tid];
    __syncthreads();

    const int p4 = tile * 256 + p;                       // float4 index in image
    const float4* xb = (const float4*)x
                     + (size_t)b * NCH * HW4 + (size_t)gofs * HW4 + p4;

    float4 bufA[8], bufB[8];
    float a0 = 0.f, a1 = 0.f, a2 = 0.f, a3 = 0.f;

    #pragma unroll
    for (int j = 0; j < 8; ++j) bufA[j] = xb[(size_t)j * HW4];

    #define PROCESS(BUF, CBASE)                                             \
        _Pragma("unroll")                                                   \
        for (int j = 0; j < 8; ++j) {                                       \
            const int c = (CBASE) + j;  /* local channel 0..127 */          \
            float4 v = BUF[j];                                              \
            float w = w3f[gofs + c];                                        \
            a0 = fmaf(v.x, w, a0); a1 = fmaf(v.y, w, a1);                   \
            a2 = fmaf(v.z, w, a2); a3 = fmaf(v.w, w, a3);                   \
            float cs = (v.x + v.y) + (v.z + v.w);                           \
            cs += __shfl_xor(cs, 1);                                        \
            cs += __shfl_xor(cs, 2);                                        \
            cs += __shfl_xor(cs, 4);                                        \
            cs += __shfl_xor(cs, 8);                                        \
            cs += __shfl_xor(cs, 16);                                       \
            cs += __shfl_xor(cs, 32);                                       \
            if (lane == 0) wsum[wave][c] = cs;                              \
        }

    for (int cb = 0; cb < 16; cb += 2) {
        #pragma unroll
        for (int j = 0; j < 8; ++j) bufB[j] = xb[(size_t)((cb + 1) * 8 + j) * HW4];
        PROCESS(bufA, cb * 8)
        if (cb + 2 < 16) {
            #pragma unroll
            for (int j = 0; j < 8; ++j) bufA[j] = xb[(size_t)((cb + 2) * 8 + j) * HW4];
        }
        PROCESS(bufB, (cb + 1) * 8)
    }
    #undef PROCESS

    __syncthreads();
    if (tid < NCH) {
        float s;
        if (tid < 128) {
            s = wsum[0][tid] + wsum[1][tid] + wsum[2][tid] + wsum[3][tid];
        } else {
            const int c = tid - 128;
            s = wsum[4][c] + wsum[5][c] + wsum[6][c] + wsum[7][c];
        }
        out[(size_t)(b * 4 + 1) * HW + tile * NCH + tid] = s;   // psum slot
    }
    if (g == 1) comb[p] = make_float4(a0, a1, a2, a3);
    __syncthreads();
    if (g == 0) {
        float4 v = comb[p];
        a0 += v.x; a1 += v.y; a2 += v.z; a3 += v.w;
        const float is2 = 0.70710678118654752440f;
        float4 r;
        r.x = 0.5f * a0 * (1.f + erff(a0 * is2));
        r.y = 0.5f * a1 * (1.f + erff(a1 * is2));
        r.z = 0.5f * a2 * (1.f + erff(a2 * is2));
        r.w = 0.5f * a3 * (1.f + erff(a3 * is2));
        ((float4*)out)[(size_t)b * 4 * HW4 + p4] = r;
    }
}

// ---------------------------------------------------------------------------
// Kernel B: per-sample tiny MLP chain: p -> g/theta/phi -> f -> y -> wy
// 16 blocks (one per b), 256 threads.
// ---------------------------------------------------------------------------
__global__ __launch_bounds__(256) void k_mlp(
    const float* outbuf,
    const float* __restrict__ Wg, const float* __restrict__ bg,
    const float* __restrict__ Wt, const float* __restrict__ bt,
    const float* __restrict__ Wp, const float* __restrict__ bp,
    const float* __restrict__ Wf, const float* __restrict__ bfv,
    const float* __restrict__ Wz, const float* __restrict__ bz,
    float* __restrict__ p_out, float* __restrict__ wy_out)
{
    const int b = blockIdx.x, tid = threadIdx.x;
    __shared__ float sp[NCH];
    __shared__ float sg[INTER], sth[INTER], sph[INTER];
    __shared__ float red[NCH];
    __shared__ float sy[INTER];
    __shared__ float sf;

    const float* psum = outbuf + (size_t)(b * 4 + 1) * HW;
    float s = 0.f;
    #pragma unroll
    for (int t = 0; t < 16; ++t) s += psum[t * NCH + tid];
    float pv = s * (1.0f / 16384.0f);
    sp[tid] = pv;
    p_out[b * NCH + tid] = pv;
    __syncthreads();

    for (int j = tid; j < 3 * INTER; j += 256) {
        const float* Wrow; float bias; int i, which;
        if (j < INTER)        { i = j;           Wrow = Wg + i * NCH; bias = bg[i]; which = 0; }
        else if (j < 2*INTER) { i = j - INTER;   Wrow = Wt + i * NCH; bias = bt[i]; which = 1; }
        else                  { i = j - 2*INTER; Wrow = Wp + i * NCH; bias = bp[i]; which = 2; }
        float acc = bias;
        for (int k = 0; k < NCH; k += 4) {
            float4 q = *(const float4*)(Wrow + k);
            acc = fmaf(q.x, sp[k+0], acc);
            acc = fmaf(q.y, sp[k+1], acc);
            acc = fmaf(q.z, sp[k+2], acc);
            acc = fmaf(q.w, sp[k+3], acc);
        }
        if (which == 0) sg[i] = acc;
        else if (which == 1) sth[i] = acc;
        else sph[i] = acc;
    }
    __syncthreads();

    float cat = (tid < INTER) ? sth[tid] : sph[tid - INTER];
    red[tid] = cat * Wf[tid];
    __syncthreads();
    if (tid == 0) {
        float acc = bfv[0];
        for (int k = 0; k < NCH; ++k) acc += red[k];
        sf = fmaxf(acc, 0.f);
    }
    __syncthreads();
    if (tid < INTER) sy[tid] = sf * sg[tid];
    __syncthreads();

    {
        const float* Wrow = Wz + tid * INTER;
        float acc = bz[tid];
        for (int k = 0; k < INTER; k += 4) {
            float4 q = *(const float4*)(Wrow + k);
            acc = fmaf(q.x, sy[k+0], acc);
            acc = fmaf(q.y, sy[k+1], acc);
            acc = fmaf(q.z, sy[k+2], acc);
            acc = fmaf(q.w, sy[k+3], acc);
        }
        wy_out[b * NCH + tid] = acc;
    }
}

// ---------------------------------------------------------------------------
// Kernel C: BatchNorm (batch stats) + residual + sigmoid + top-3 selection.
// 16 blocks (one per b), 256 threads. Writes sel[b][3] to ws; NO gather here.
// ---------------------------------------------------------------------------
__global__ __launch_bounds__(256) void k_bn_topk(
    const float* __restrict__ wy, const float* __restrict__ p,
    const float* __restrict__ gamma, const float* __restrict__ beta,
    int* __restrict__ sel_out)
{
    const int b = blockIdx.x, tid = threadIdx.x;
    const int wave = tid >> 6, lane = tid & 63;
    __shared__ float wsc[4];
    __shared__ int   wid[4];
    __shared__ int   sel[3];

    float vv[16];
    float mu = 0.f;
    #pragma unroll
    for (int bb = 0; bb < 16; ++bb) { vv[bb] = wy[bb * NCH + tid]; mu += vv[bb]; }
    mu *= (1.f / 16.f);
    float var = 0.f;
    #pragma unroll
    for (int bb = 0; bb < 16; ++bb) { float d = vv[bb] - mu; var = fmaf(d, d, var); }
    var *= (1.f / 16.f);

    float bn = gamma[tid] * (vv[b] - mu) * rsqrtf(var + 1e-5f) + beta[tid];
    float z  = bn + p[b * NCH + tid];
    float sc = 1.f / (1.f + expf(-z));

    for (int r = 0; r < 3; ++r) {
        float s = sc; int id = tid;
        #pragma unroll
        for (int m = 1; m <= 32; m <<= 1) {
            float so = __shfl_xor(s, m);
            int   io = __shfl_xor(id, m);
            if (so > s || (so == s && io < id)) { s = so; id = io; }
        }
        if (lane == 0) { wsc[wave] = s; wid[wave] = id; }
        __syncthreads();
        if (tid == 0) {
            float bs = wsc[0]; int bi = wid[0];
            for (int w = 1; w < 4; ++w)
                if (wsc[w] > bs || (wsc[w] == bs && wid[w] < bi)) { bs = wsc[w]; bi = wid[w]; }
            sel[r] = bi;
        }
        __syncthreads();
        if (tid == sel[r]) sc = -1e30f;
        __syncthreads();
    }
    if (tid < 3) sel_out[b * 3 + tid] = sel[tid];
}

// ---------------------------------------------------------------------------
// Kernel D: gather top-3 channels, spread over 192 blocks (4 seg x 3 r x 16 b)
// 16 KB copied per block, float4, bit-exact.
// ---------------------------------------------------------------------------
__global__ __launch_bounds__(256) void k_gather(
    const float* __restrict__ x, const int* __restrict__ sel,
    float* __restrict__ out)
{
    const int seg = blockIdx.x;   // 4
    const int r   = blockIdx.y;   // 3
    const int b   = blockIdx.z;   // 16
    const int ch  = sel[b * 3 + r];
    const float4* src = (const float4*)x + (size_t)(b * NCH + ch) * HW4 + seg * 1024;
    float4*       dst = (float4*)out + (size_t)(b * 4 + 1 + r) * HW4 + seg * 1024;
    #pragma unroll
    for (int i = 0; i < 4; ++i)
        dst[i * 256 + threadIdx.x] = src[i * 256 + threadIdx.x];
}

extern "C" void kernel_launch(void* const* d_in, const int* in_sizes, int n_in,
                              void* d_out, int out_size, void* d_ws, size_t ws_size,
                              hipStream_t stream)
{
    const float* x     = (const float*)d_in[0];
    const float* Wg    = (const float*)d_in[1];
    const float* bg    = (const float*)d_in[2];
    const float* Wt    = (const float*)d_in[3];
    const float* bt    = (const float*)d_in[4];
    const float* Wp    = (const float*)d_in[5];
    const float* bp    = (const float*)d_in[6];
    const float* Wf    = (const float*)d_in[7];
    const float* bfv   = (const float*)d_in[8];
    const float* Wz    = (const float*)d_in[9];
    const float* bz    = (const float*)d_in[10];
    const float* gamma = (const float*)d_in[11];
    const float* beta  = (const float*)d_in[12];
    const float* W3    = (const float*)d_in[13];
    float* out = (float*)d_out;

    // d_ws: wy[16][256] f32 | p[16][256] f32 | sel[16][3] int
    float* wy  = (float*)d_ws;
    float* p   = wy + NB * NCH;
    int*   sel = (int*)(p + NB * NCH);

    k_pool_x3<<<dim3(16, 16), 512, 0, stream>>>(x, W3, out);
    k_mlp<<<NB, 256, 0, stream>>>(out, Wg, bg, Wt, bt, Wp, bp, Wf, bfv, Wz, bz, p, wy);
    k_bn_topk<<<NB, 256, 0, stream>>>(wy, p, gamma, beta, sel);
    k_gather<<<dim3(4, 3, NB), 256, 0, stream>>>(x, sel, out);
}

// Round 3
// 396.135 us; speedup vs baseline: 1.0600x; 1.0277x over previous
//
#include <hip/hip_runtime.h>

#define HW    16384   // 128*128
#define NCH   256     // C
#define NB    16      // batch
#define INTER 128
#define HW4   4096    // HW/4 (float4 units)
#define WSTR  34      // wsum row stride (32 lane-partials + pad)

// Output: [16, 4, 128, 128] f32.
//   out[b,0]    = gelu_exact(sum_c x[b,c,:,:] * W3[c])
//   out[b,1..3] = x[b, top3_ch_r, :, :]
// psum[b] (16 KB) borrows d_out's channel-1 slot between kernels A and B.

// ---------------------------------------------------------------------------
// Kernel A: fused pool + x3 pass over x (268 MB).
// grid (16 tiles, 16 b), 512 threads. Each WAVE owns 32 channels over the
// whole 256-float4 tile (4 position-iters/channel), so each thread
// accumulates 16 pixels per channel in a register before ANY cross-lane
// traffic: 1 shfl + 1 ds_write per channel (was 6-deep shfl chain per 4
// pixels = 768 DS ops/thread; now 48). Pool lane-sum finished in one LDS
// reduce pass; per-pixel x3 partials combined across waves via comb[7][256].
// ---------------------------------------------------------------------------
__global__ __launch_bounds__(512, 2) void k_pool_x3(
    const float* __restrict__ x, const float* __restrict__ W3, float* out)
{
    const int tile = blockIdx.x;
    const int b    = blockIdx.y;
    const int tid  = threadIdx.x;
    const int wave = tid >> 6, lane = tid & 63;
    const int c0   = wave << 5;            // this wave's first channel

    __shared__ float  w3f[NCH];            // 1 KB
    __shared__ float  wsum[NCH * WSTR];    // 34 KB: [channel][32 lane-partials]
    __shared__ float4 comb[7][256];        // 28 KB: x3 partials of waves 1..7

    if (tid < NCH) w3f[tid] = W3[tid];
    __syncthreads();

    // base: batch b, channel c0, float4-position tile*256 + lane
    const float4* xb = (const float4*)x + (size_t)b * NCH * HW4
                     + (size_t)c0 * HW4 + tile * 256 + lane;

    float4 a[4];                           // x3 partial per position-iter q
    #pragma unroll
    for (int q = 0; q < 4; ++q) a[q] = make_float4(0.f, 0.f, 0.f, 0.f);

    float4 bufA[8], bufB[8];               // 2 channels x 4 position-iters each
    #pragma unroll
    for (int j = 0; j < 8; ++j)
        bufA[j] = xb[(size_t)(j >> 2) * HW4 + (j & 3) * 64];

    // Process channel pair (CBASE, CBASE+1) from BUF; j = h*4 + q.
    #define PROCESS(BUF, CBASE)                                             \
        _Pragma("unroll")                                                   \
        for (int h = 0; h < 2; ++h) {                                       \
            const int c = (CBASE) + h;                                      \
            const float w = w3f[c0 + c];                                    \
            float cs = 0.f;                                                 \
            _Pragma("unroll")                                               \
            for (int q = 0; q < 4; ++q) {                                   \
                float4 v = BUF[h * 4 + q];                                  \
                a[q].x = fmaf(v.x, w, a[q].x);                              \
                a[q].y = fmaf(v.y, w, a[q].y);                              \
                a[q].z = fmaf(v.z, w, a[q].z);                              \
                a[q].w = fmaf(v.w, w, a[q].w);                              \
                cs += (v.x + v.y) + (v.z + v.w);                            \
            }                                                               \
            cs += __shfl_xor(cs, 32);                                       \
            if (lane < 32) wsum[(c0 + c) * WSTR + lane] = cs;               \
        }

    for (int cc = 0; cc < 32; cc += 4) {
        #pragma unroll
        for (int j = 0; j < 8; ++j)
            bufB[j] = xb[(size_t)(cc + 2 + (j >> 2)) * HW4 + (j & 3) * 64];
        PROCESS(bufA, cc)
        if (cc + 4 < 32) {
            #pragma unroll
            for (int j = 0; j < 8; ++j)
                bufA[j] = xb[(size_t)(cc + 4 + (j >> 2)) * HW4 + (j & 3) * 64];
        }
        PROCESS(bufB, cc + 2)
    }
    #undef PROCESS

    __syncthreads();

    // pool reduce: 2 threads per channel, 16 lane-partials each
    {
        const int ch = tid >> 1, half = tid & 1;
        const float* rowp = &wsum[ch * WSTR + half * 16];
        float s = 0.f;
        #pragma unroll
        for (int k = 0; k < 8; ++k) {
            float2 v2 = *(const float2*)(rowp + k * 2);
            s += v2.x + v2.y;
        }
        s += __shfl_xor(s, 1);
        if (half == 0)
            out[(size_t)(b * 4 + 1) * HW + tile * NCH + ch] = s;  // psum slot
    }

    // x3 cross-wave combine: waves 1..7 dump, wave 0 finishes
    if (wave > 0) {
        #pragma unroll
        for (int q = 0; q < 4; ++q) comb[wave - 1][q * 64 + lane] = a[q];
    }
    __syncthreads();
    if (wave == 0) {
        #pragma unroll
        for (int j = 0; j < 7; ++j) {
            #pragma unroll
            for (int q = 0; q < 4; ++q) {
                float4 v = comb[j][q * 64 + lane];
                a[q].x += v.x; a[q].y += v.y; a[q].z += v.z; a[q].w += v.w;
            }
        }
        const float is2 = 0.70710678118654752440f;
        #pragma unroll
        for (int q = 0; q < 4; ++q) {
            float4 r;
            r.x = 0.5f * a[q].x * (1.f + erff(a[q].x * is2));
            r.y = 0.5f * a[q].y * (1.f + erff(a[q].y * is2));
            r.z = 0.5f * a[q].z * (1.f + erff(a[q].z * is2));
            r.w = 0.5f * a[q].w * (1.f + erff(a[q].w * is2));
            ((float4*)out)[(size_t)b * 4 * HW4 + tile * 256 + q * 64 + lane] = r;
        }
    }
}

// ---------------------------------------------------------------------------
// Kernel B: per-sample tiny MLP chain: p -> g/theta/phi -> f -> y -> wy
// 16 blocks (one per b), 256 threads.
// ---------------------------------------------------------------------------
__global__ __launch_bounds__(256) void k_mlp(
    const float* outbuf,
    const float* __restrict__ Wg, const float* __restrict__ bg,
    const float* __restrict__ Wt, const float* __restrict__ bt,
    const float* __restrict__ Wp, const float* __restrict__ bp,
    const float* __restrict__ Wf, const float* __restrict__ bfv,
    const float* __restrict__ Wz, const float* __restrict__ bz,
    float* __restrict__ p_out, float* __restrict__ wy_out)
{
    const int b = blockIdx.x, tid = threadIdx.x;
    __shared__ float sp[NCH];
    __shared__ float sg[INTER], sth[INTER], sph[INTER];
    __shared__ float red[NCH];
    __shared__ float sy[INTER];
    __shared__ float sf;

    const float* psum = outbuf + (size_t)(b * 4 + 1) * HW;
    float s = 0.f;
    #pragma unroll
    for (int t = 0; t < 16; ++t) s += psum[t * NCH + tid];
    float pv = s * (1.0f / 16384.0f);
    sp[tid] = pv;
    p_out[b * NCH + tid] = pv;
    __syncthreads();

    for (int j = tid; j < 3 * INTER; j += 256) {
        const float* Wrow; float bias; int i, which;
        if (j < INTER)        { i = j;           Wrow = Wg + i * NCH; bias = bg[i]; which = 0; }
        else if (j < 2*INTER) { i = j - INTER;   Wrow = Wt + i * NCH; bias = bt[i]; which = 1; }
        else                  { i = j - 2*INTER; Wrow = Wp + i * NCH; bias = bp[i]; which = 2; }
        float acc = bias;
        for (int k = 0; k < NCH; k += 4) {
            float4 q = *(const float4*)(Wrow + k);
            acc = fmaf(q.x, sp[k+0], acc);
            acc = fmaf(q.y, sp[k+1], acc);
            acc = fmaf(q.z, sp[k+2], acc);
            acc = fmaf(q.w, sp[k+3], acc);
        }
        if (which == 0) sg[i] = acc;
        else if (which == 1) sth[i] = acc;
        else sph[i] = acc;
    }
    __syncthreads();

    float cat = (tid < INTER) ? sth[tid] : sph[tid - INTER];
    red[tid] = cat * Wf[tid];
    __syncthreads();
    if (tid == 0) {
        float acc = bfv[0];
        for (int k = 0; k < NCH; ++k) acc += red[k];
        sf = fmaxf(acc, 0.f);
    }
    __syncthreads();
    if (tid < INTER) sy[tid] = sf * sg[tid];
    __syncthreads();

    {
        const float* Wrow = Wz + tid * INTER;
        float acc = bz[tid];
        for (int k = 0; k < INTER; k += 4) {
            float4 q = *(const float4*)(Wrow + k);
            acc = fmaf(q.x, sy[k+0], acc);
            acc = fmaf(q.y, sy[k+1], acc);
            acc = fmaf(q.z, sy[k+2], acc);
            acc = fmaf(q.w, sy[k+3], acc);
        }
        wy_out[b * NCH + tid] = acc;
    }
}

// ---------------------------------------------------------------------------
// Kernel C: BatchNorm (batch stats) + residual + sigmoid + top-3 selection.
// 16 blocks (one per b), 256 threads. Writes sel[b][3] to ws; NO gather here.
// ---------------------------------------------------------------------------
__global__ __launch_bounds__(256) void k_bn_topk(
    const float* __restrict__ wy, const float* __restrict__ p,
    const float* __restrict__ gamma, const float* __restrict__ beta,
    int* __restrict__ sel_out)
{
    const int b = blockIdx.x, tid = threadIdx.x;
    const int wave = tid >> 6, lane = tid & 63;
    __shared__ float wsc[4];
    __shared__ int   wid[4];
    __shared__ int   sel[3];

    float vv[16];
    float mu = 0.f;
    #pragma unroll
    for (int bb = 0; bb < 16; ++bb) { vv[bb] = wy[bb * NCH + tid]; mu += vv[bb]; }
    mu *= (1.f / 16.f);
    float var = 0.f;
    #pragma unroll
    for (int bb = 0; bb < 16; ++bb) { float d = vv[bb] - mu; var = fmaf(d, d, var); }
    var *= (1.f / 16.f);

    float bn = gamma[tid] * (vv[b] - mu) * rsqrtf(var + 1e-5f) + beta[tid];
    float z  = bn + p[b * NCH + tid];
    float sc = 1.f / (1.f + expf(-z));

    for (int r = 0; r < 3; ++r) {
        float s = sc; int id = tid;
        #pragma unroll
        for (int m = 1; m <= 32; m <<= 1) {
            float so = __shfl_xor(s, m);
            int   io = __shfl_xor(id, m);
            if (so > s || (so == s && io < id)) { s = so; id = io; }
        }
        if (lane == 0) { wsc[wave] = s; wid[wave] = id; }
        __syncthreads();
        if (tid == 0) {
            float bs = wsc[0]; int bi = wid[0];
            for (int w = 1; w < 4; ++w)
                if (wsc[w] > bs || (wsc[w] == bs && wid[w] < bi)) { bs = wsc[w]; bi = wid[w]; }
            sel[r] = bi;
        }
        __syncthreads();
        if (tid == sel[r]) sc = -1e30f;
        __syncthreads();
    }
    if (tid < 3) sel_out[b * 3 + tid] = sel[tid];
}

// ---------------------------------------------------------------------------
// Kernel D: gather top-3 channels, spread over 192 blocks (4 seg x 3 r x 16 b)
// 16 KB copied per block, float4, bit-exact.
// ---------------------------------------------------------------------------
__global__ __launch_bounds__(256) void k_gather(
    const float* __restrict__ x, const int* __restrict__ sel,
    float* __restrict__ out)
{
    const int seg = blockIdx.x;   // 4
    const int r   = blockIdx.y;   // 3
    const int b   = blockIdx.z;   // 16
    const int ch  = sel[b * 3 + r];
    const float4* src = (const float4*)x + (size_t)(b * NCH + ch) * HW4 + seg * 1024;
    float4*       dst = (float4*)out + (size_t)(b * 4 + 1 + r) * HW4 + seg * 1024;
    #pragma unroll
    for (int i = 0; i < 4; ++i)
        dst[i * 256 + threadIdx.x] = src[i * 256 + threadIdx.x];
}

extern "C" void kernel_launch(void* const* d_in, const int* in_sizes, int n_in,
                              void* d_out, int out_size, void* d_ws, size_t ws_size,
                              hipStream_t stream)
{
    const float* x     = (const float*)d_in[0];
    const float* Wg    = (const float*)d_in[1];
    const float* bg    = (const float*)d_in[2];
    const float* Wt    = (const float*)d_in[3];
    const float* bt    = (const float*)d_in[4];
    const float* Wp    = (const float*)d_in[5];
    const float* bp    = (const float*)d_in[6];
    const float* Wf    = (const float*)d_in[7];
    const float* bfv   = (const float*)d_in[8];
    const float* Wz    = (const float*)d_in[9];
    const float* bz    = (const float*)d_in[10];
    const float* gamma = (const float*)d_in[11];
    const float* beta  = (const float*)d_in[12];
    const float* W3    = (const float*)d_in[13];
    float* out = (float*)d_out;

    // d_ws: wy[16][256] f32 | p[16][256] f32 | sel[16][3] int
    float* wy  = (float*)d_ws;
    float* p   = wy + NB * NCH;
    int*   sel = (int*)(p + NB * NCH);

    k_pool_x3<<<dim3(16, 16), 512, 0, stream>>>(x, W3, out);
    k_mlp<<<NB, 256, 0, stream>>>(out, Wg, bg, Wt, bt, Wp, bp, Wf, bfv, Wz, bz, p, wy);
    k_bn_topk<<<NB, 256, 0, stream>>>(wy, p, gamma, beta, sel);
    k_gather<<<dim3(4, 3, NB), 256, 0, stream>>>(x, sel, out);
}